// Round 6
// baseline (790.448 us; speedup 1.0000x reference)
//
#include <hip/hip_runtime.h>
#include <hip/hip_bf16.h>

#define HWv   35840   // H*W = 160*224
#define NPTS  35840
#define Bv    2
#define Kv    16
#define CP3   67
#define COUT  64
#define PPB   16
#define NBLK_PER_B (NPTS / PPB)   // 2240
#define KDIM  1088    // 16 f * 68 c   (c: 0-63 features, 64-66 xyz, 67 pad)
#define KHALF 544     // 8 f * 68 c per stage
#define ASTRH 552     // half-row stride in bf16 (1104 B, 16B-aligned)
#define WTSTR 264     // sWt p-stride in f32

typedef __attribute__((ext_vector_type(4))) float  f32x4;
typedef __attribute__((ext_vector_type(8))) short  bf16x8;

static __device__ __forceinline__ unsigned short f2bf(float f) {
    unsigned int u = __float_as_uint(f);
    unsigned int r = (u + 0x7FFFu + ((u >> 16) & 1u)) >> 16;   // RNE
    return (unsigned short)r;
}
static __device__ __forceinline__ float bf2f(unsigned short s) {
    return __uint_as_float((unsigned int)s << 16);
}
static __device__ __forceinline__ float leaky(float v) { return v >= 0.f ? v : 0.1f * v; }

// ---- kernel 1: channel-last bf16 features [B][HW][64] + f32 xyz [B][HW][4] ----
__global__ __launch_bounds__(256) void transpose_kernel(const float* __restrict__ xyz,
                                                        const float* __restrict__ feat,
                                                        unsigned short* __restrict__ feats_bf,
                                                        float* __restrict__ xyz_cl) {
    __shared__ float tile[68][65];
    int t = threadIdx.x;
    int blk = blockIdx.x;                 // Bv * 560
    int b = blk / 560;
    int hw0 = (blk % 560) * 64;
    int j = t & 63, cq = t >> 6;
    for (int cc = 0; cc < 17; ++cc) {
        int c = cc * 4 + cq;              // 0..67
        float v = 0.f;
        if (c < 64)      v = feat[((long)b * 64 + c) * HWv + hw0 + j];
        else if (c < 67) v = xyz[((long)b * 3 + (c - 64)) * HWv + hw0 + j];
        tile[c][j] = v;
    }
    __syncthreads();
    int r = t >> 2, q = t & 3;
    unsigned short* dst = feats_bf + ((long)b * HWv + hw0 + r) * 64;
    #pragma unroll
    for (int i = q; i < 16; i += 4) {
        ushort4 v;
        v.x = f2bf(tile[i * 4 + 0][r]); v.y = f2bf(tile[i * 4 + 1][r]);
        v.z = f2bf(tile[i * 4 + 2][r]); v.w = f2bf(tile[i * 4 + 3][r]);
        *(ushort4*)(dst + i * 4) = v;
    }
    if (q == 0) {
        float4 x4 = make_float4(tile[64][r], tile[65][r], tile[66][r], 0.f);
        *(float4*)(xyz_cl + ((long)b * HWv + hw0 + r) * 4) = x4;
    }
}

// ---- kernel 1b: w_lin -> bf16 [64][1088], channel-remapped to match sAgg ----
__global__ __launch_bounds__(256) void wl_bf16_kernel(const float* __restrict__ w_lin,
                                                      unsigned short* __restrict__ wl_bf) {
    int e = blockIdx.x * 256 + threadIdx.x;   // 64*1088 = 69632
    if (e >= COUT * KDIM) return;
    int o  = e / KDIM;
    int fc = e - o * KDIM;
    int f  = fc / 68;
    int c  = fc - f * 68;
    float v = 0.f;
    if (c < 64)      v = w_lin[o * (16 * CP3) + f * CP3 + 3 + c];    // feature channels
    else if (c < 67) v = w_lin[o * (16 * CP3) + f * CP3 + (c - 64)]; // xyz channels
    wl_bf[e] = f2bf(v);
}

// ---- kernel 2: fused gather + weightnet + agg + staged MFMA linear ----
__global__ __launch_bounds__(256, 5) void pointconv_main(
        const unsigned short* __restrict__ feats_bf,
        const float*  __restrict__ xyz_cl,
        const unsigned short* __restrict__ wl_bf,
        const int*    __restrict__ knn_idx,
        const int*    __restrict__ mask,
        const float*  __restrict__ sampled,
        const float*  __restrict__ w1,
        const float*  __restrict__ b1,
        const float*  __restrict__ w2,
        const float*  __restrict__ b2,
        const float*  __restrict__ b_lin,
        float*        __restrict__ out) {
    // lifetime-union: [sXyz 3072 | sWt 16896] (P0-P2) overlaid by sAggH 17664 (stages)
    __shared__ __align__(16) char sBuf[19968];
    __shared__ int   sRow[PPB][Kv];
    __shared__ float sNx[PPB][4];
    __shared__ float sNet[240];        // w1(24) b1(8) w2(128) b2(16) b_lin(64)

    float* sXyz = (float*)sBuf;                      // [p][k][3]
    float* sWt  = (float*)(sBuf + 3072);             // [p][k*16+f], p-stride 264
    unsigned short* sAggH = (unsigned short*)sBuf;   // [16 pts][552] bf16, per stage

    int t = threadIdx.x;
    int blk = blockIdx.x;
    int b = blk / NBLK_PER_B;
    int n0 = (blk % NBLK_PER_B) * PPB;
    int p = t >> 4, u = t & 15;
    int w = t >> 6, l = t & 63;

    // ---- P0: metadata + params ----
    int base = (b * NPTS + n0 + p) * Kv + u;
    int g = knn_idx[base];
    float mf = mask[base] ? 1.f : 0.f;
    int row = b * HWv + g;
    sRow[p][u] = row * 128;                          // byte offset into feats_bf
    float4 x4 = *(const float4*)(xyz_cl + (long)row * 4);
    float xd0 = x4.x * mf, xd1 = x4.y * mf, xd2 = x4.z * mf;
    {
        float* xs = sXyz + (p * Kv + u) * 3;
        xs[0] = xd0; xs[1] = xd1; xs[2] = xd2;
    }
    if (t < 240) {
        float v;
        if (t < 24)       v = w1[t];
        else if (t < 32)  v = b1[t - 24];
        else if (t < 160) v = w2[t - 32];
        else if (t < 176) v = b2[t - 160];
        else              v = b_lin[t - 176];
        sNet[t] = v;
    }
    if (t < PPB * 3) { int pp = t / 3, c = t - pp * 3; sNx[pp][c] = sampled[(b * 3 + c) * HWv + n0 + pp]; }
    __syncthreads();

    // ---- P1: weight net, thread = (p,k=u); coords from own registers ----
    {
        const float* W1 = sNet;
        const float* B1 = sNet + 24;
        const float* W2 = sNet + 32;
        const float* B2 = sNet + 160;
        float r0 = xd0 - sNx[p][0];
        float r1 = xd1 - sNx[p][1];
        float r2 = xd2 - sNx[p][2];
        float h[8];
        #pragma unroll
        for (int i = 0; i < 8; ++i)
            h[i] = leaky(W1[i * 3] * r0 + W1[i * 3 + 1] * r1 + W1[i * 3 + 2] * r2 + B1[i]);
        float wk[16];
        #pragma unroll
        for (int f = 0; f < 16; ++f) {
            float v = B2[f];
            #pragma unroll
            for (int i = 0; i < 8; ++i) v += W2[f * 8 + i] * h[i];
            wk[f] = leaky(v) * mf;                   // mask folded into weight
        }
        f32x4* wdst = (f32x4*)(sWt + p * WTSTR + u * 16);
        wdst[0] = (f32x4){wk[0], wk[1], wk[2], wk[3]};
        wdst[1] = (f32x4){wk[4], wk[5], wk[6], wk[7]};
        wdst[2] = (f32x4){wk[8], wk[9], wk[10], wk[11]};
        wdst[3] = (f32x4){wk[12], wk[13], wk[14], wk[15]};
    }
    __syncthreads();

    // ---- P2: aggregation. thread = (p,u); u owns feature channels 4u..4u+3 ----
    float agg[16][4];
    #pragma unroll
    for (int f = 0; f < 16; ++f)
        #pragma unroll
        for (int c = 0; c < 4; ++c) agg[f][c] = 0.f;
    float ax = 0.f, ay = 0.f, az = 0.f;              // xyz-channel agg (f = u role)

    const char* fb = (const char*)feats_bf;
    #pragma unroll
    for (int k = 0; k < Kv; ++k) {
        ushort4 hv = *(const ushort4*)(fb + sRow[p][k] + u * 8);
        float fv0 = bf2f(hv.x), fv1 = bf2f(hv.y), fv2 = bf2f(hv.z), fv3 = bf2f(hv.w);
        const f32x4* wt4 = (const f32x4*)(sWt + p * WTSTR + k * 16);
        f32x4 w0 = wt4[0], w1v = wt4[1], w2v = wt4[2], w3v = wt4[3];
        #pragma unroll
        for (int c = 0; c < 4; ++c) {
            float fv = c == 0 ? fv0 : c == 1 ? fv1 : c == 2 ? fv2 : fv3;
            agg[0][c]  += w0[0] * fv;  agg[1][c]  += w0[1] * fv;
            agg[2][c]  += w0[2] * fv;  agg[3][c]  += w0[3] * fv;
            agg[4][c]  += w1v[0] * fv; agg[5][c]  += w1v[1] * fv;
            agg[6][c]  += w1v[2] * fv; agg[7][c]  += w1v[3] * fv;
            agg[8][c]  += w2v[0] * fv; agg[9][c]  += w2v[1] * fv;
            agg[10][c] += w2v[2] * fv; agg[11][c] += w2v[3] * fv;
            agg[12][c] += w3v[0] * fv; agg[13][c] += w3v[1] * fv;
            agg[14][c] += w3v[2] * fv; agg[15][c] += w3v[3] * fv;
        }
        float wtv = sWt[p * WTSTR + k * 16 + u];
        const float* xs = sXyz + (p * Kv + k) * 3;
        ax += wtv * xs[0]; ay += wtv * xs[1]; az += wtv * xs[2];
    }
    __syncthreads();      // sWt/sXyz dead; sAggH may overlay

    // ---- staged MFMA: two f-halves, each 16 pts x 544 K ----
    int row16 = l & 15;
    int kgrp  = l >> 4;
    f32x4 acc0 = {0.f, 0.f, 0.f, 0.f}, acc1 = {0.f, 0.f, 0.f, 0.f};

    #pragma unroll
    for (int hstage = 0; hstage < 2; ++hstage) {
        // write half hstage: f = hstage*8 + fl
        #pragma unroll
        for (int fl = 0; fl < 8; ++fl) {
            ushort4 hv;
            hv.x = f2bf(agg[hstage * 8 + fl][0]); hv.y = f2bf(agg[hstage * 8 + fl][1]);
            hv.z = f2bf(agg[hstage * 8 + fl][2]); hv.w = f2bf(agg[hstage * 8 + fl][3]);
            *(ushort4*)&sAggH[p * ASTRH + fl * 68 + u * 4] = hv;
        }
        if ((u >> 3) == hstage) {                    // xyz channels for f = u
            ushort4 hx;
            hx.x = f2bf(ax); hx.y = f2bf(ay); hx.z = f2bf(az); hx.w = 0;
            *(ushort4*)&sAggH[p * ASTRH + (u & 7) * 68 + 64] = hx;
        }
        __syncthreads();
        // MFMA over this half: K = 544 = 17 x 32
        const bf16x8* aptr = (const bf16x8*)&sAggH[row16 * ASTRH + kgrp * 8];
        const bf16x8* bptr = (const bf16x8*)(wl_bf + (w * 16 + row16) * KDIM + hstage * KHALF + kgrp * 8);
        if (hstage == 0) {
            #pragma unroll
            for (int kt = 0; kt < 17; ++kt)
                acc0 = __builtin_amdgcn_mfma_f32_16x16x32_bf16(aptr[kt * 4], bptr[kt * 4], acc0, 0, 0, 0);
            __syncthreads();                         // half0 reads done before overwrite
        } else {
            #pragma unroll
            for (int kt = 0; kt < 17; ++kt)
                acc1 = __builtin_amdgcn_mfma_f32_16x16x32_bf16(aptr[kt * 4], bptr[kt * 4], acc1, 0, 0, 0);
        }
    }

    // ---- store ----
    {
        f32x4 acc = acc0 + acc1;
        int o = w * 16 + row16;
        float bias = sNet[176 + o];
        float4 res;
        res.x = leaky(acc[0] + bias);
        res.y = leaky(acc[1] + bias);
        res.z = leaky(acc[2] + bias);
        res.w = leaky(acc[3] + bias);
        *(float4*)(out + (long)(b * COUT + o) * HWv + n0 + kgrp * 4) = res;
    }
}

extern "C" void kernel_launch(void* const* d_in, const int* in_sizes, int n_in,
                              void* d_out, int out_size, void* d_ws, size_t ws_size,
                              hipStream_t stream) {
    const float* xyz      = (const float*)d_in[0];
    const float* features = (const float*)d_in[1];
    const float* sampled  = (const float*)d_in[2];
    const int*   knn_idx  = (const int*)  d_in[3];
    const int*   mask     = (const int*)  d_in[4];
    const float* w1       = (const float*)d_in[5];
    const float* b1       = (const float*)d_in[6];
    const float* w2       = (const float*)d_in[7];
    const float* b2       = (const float*)d_in[8];
    const float* w_lin    = (const float*)d_in[9];
    const float* b_lin    = (const float*)d_in[10];
    float* out = (float*)d_out;

    unsigned short* feats_bf = (unsigned short*)d_ws;
    float* xyz_cl = (float*)((char*)d_ws + (size_t)Bv * HWv * 64 * 2);
    unsigned short* wl_bf = (unsigned short*)((char*)xyz_cl + (size_t)Bv * HWv * 4 * 4);

    transpose_kernel<<<Bv * 560, 256, 0, stream>>>(xyz, features, feats_bf, xyz_cl);
    wl_bf16_kernel<<<(COUT * KDIM + 255) / 256, 256, 0, stream>>>(w_lin, wl_bf);
    pointconv_main<<<Bv * NBLK_PER_B, 256, 0, stream>>>(feats_bf, xyz_cl, wl_bf, knn_idx, mask,
                                                        sampled, w1, b1, w2, b2, b_lin, out);
}

// Round 7
// 515.370 us; speedup vs baseline: 1.5337x; 1.5337x over previous
//
#include <hip/hip_runtime.h>
#include <hip/hip_bf16.h>

#define HWv   35840   // H*W = 160*224
#define NPTS  35840
#define Bv    2
#define Kv    16
#define CP3   67
#define COUT  64
#define PPB   16
#define NBLK_PER_B (NPTS / PPB)   // 2240
#define KDIM  1088    // 16 f * 68 c   (c: 0-63 features, 64-66 xyz, 67 pad)
#define KHALF 544     // 8 f * 68 c per stage
#define ASTRH 552     // half-row stride in bf16 (1104 B, 16B-aligned)
#define WTSTR 264     // sWt p-stride in f32

typedef __attribute__((ext_vector_type(4))) float  f32x4;
typedef __attribute__((ext_vector_type(8))) short  bf16x8;

static __device__ __forceinline__ unsigned short f2bf(float f) {
    unsigned int u = __float_as_uint(f);
    unsigned int r = (u + 0x7FFFu + ((u >> 16) & 1u)) >> 16;   // RNE
    return (unsigned short)r;
}
static __device__ __forceinline__ float bf2f(unsigned short s) {
    return __uint_as_float((unsigned int)s << 16);
}
static __device__ __forceinline__ float leaky(float v) { return v >= 0.f ? v : 0.1f * v; }

// ---- kernel 1: channel-last bf16 features [B][HW][64] + f32 xyz [B][HW][4] ----
__global__ __launch_bounds__(256) void transpose_kernel(const float* __restrict__ xyz,
                                                        const float* __restrict__ feat,
                                                        unsigned short* __restrict__ feats_bf,
                                                        float* __restrict__ xyz_cl) {
    __shared__ float tile[68][65];
    int t = threadIdx.x;
    int blk = blockIdx.x;                 // Bv * 560
    int b = blk / 560;
    int hw0 = (blk % 560) * 64;
    int j = t & 63, cq = t >> 6;
    for (int cc = 0; cc < 17; ++cc) {
        int c = cc * 4 + cq;              // 0..67
        float v = 0.f;
        if (c < 64)      v = feat[((long)b * 64 + c) * HWv + hw0 + j];
        else if (c < 67) v = xyz[((long)b * 3 + (c - 64)) * HWv + hw0 + j];
        tile[c][j] = v;
    }
    __syncthreads();
    int r = t >> 2, q = t & 3;
    unsigned short* dst = feats_bf + ((long)b * HWv + hw0 + r) * 64;
    #pragma unroll
    for (int i = q; i < 16; i += 4) {
        ushort4 v;
        v.x = f2bf(tile[i * 4 + 0][r]); v.y = f2bf(tile[i * 4 + 1][r]);
        v.z = f2bf(tile[i * 4 + 2][r]); v.w = f2bf(tile[i * 4 + 3][r]);
        *(ushort4*)(dst + i * 4) = v;
    }
    if (q == 0) {
        float4 x4 = make_float4(tile[64][r], tile[65][r], tile[66][r], 0.f);
        *(float4*)(xyz_cl + ((long)b * HWv + hw0 + r) * 4) = x4;
    }
}

// ---- kernel 1b: w_lin -> bf16 [64][1088], channel-remapped to match sAgg ----
__global__ __launch_bounds__(256) void wl_bf16_kernel(const float* __restrict__ w_lin,
                                                      unsigned short* __restrict__ wl_bf) {
    int e = blockIdx.x * 256 + threadIdx.x;   // 64*1088 = 69632
    if (e >= COUT * KDIM) return;
    int o  = e / KDIM;
    int fc = e - o * KDIM;
    int f  = fc / 68;
    int c  = fc - f * 68;
    float v = 0.f;
    if (c < 64)      v = w_lin[o * (16 * CP3) + f * CP3 + 3 + c];    // feature channels
    else if (c < 67) v = w_lin[o * (16 * CP3) + f * CP3 + (c - 64)]; // xyz channels
    wl_bf[e] = f2bf(v);
}

// ---- kernel 2: fused gather + weightnet + agg + staged MFMA linear ----
__global__ __launch_bounds__(256, 4) void pointconv_main(
        const unsigned short* __restrict__ feats_bf,
        const float*  __restrict__ xyz_cl,
        const unsigned short* __restrict__ wl_bf,
        const int*    __restrict__ knn_idx,
        const int*    __restrict__ mask,
        const float*  __restrict__ sampled,
        const float*  __restrict__ w1,
        const float*  __restrict__ b1,
        const float*  __restrict__ w2,
        const float*  __restrict__ b2,
        const float*  __restrict__ b_lin,
        float*        __restrict__ out) {
    // lifetime-union: [sXyz 3072 | sWt 16896] (P0-P2) overlaid by sAggH 17664 (stages)
    __shared__ __align__(16) char sBuf[19968];
    __shared__ int   sRow[PPB][Kv];
    __shared__ float sNx[PPB][4];
    __shared__ float sNet[240];        // w1(24) b1(8) w2(128) b2(16) b_lin(64)

    float* sXyz = (float*)sBuf;                      // [p][k][3]
    float* sWt  = (float*)(sBuf + 3072);             // [p][k*16+f], p-stride 264
    unsigned short* sAggH = (unsigned short*)sBuf;   // [16 pts][552] bf16, per stage

    int t = threadIdx.x;
    int blk = blockIdx.x;
    int b = blk / NBLK_PER_B;
    int n0 = (blk % NBLK_PER_B) * PPB;
    int p = t >> 4, u = t & 15;
    int w = t >> 6, l = t & 63;

    // ---- P0: metadata + params ----
    int base = (b * NPTS + n0 + p) * Kv + u;
    int g = knn_idx[base];
    float mf = mask[base] ? 1.f : 0.f;
    int row = b * HWv + g;
    sRow[p][u] = row * 128;                          // byte offset into feats_bf
    float4 x4 = *(const float4*)(xyz_cl + (long)row * 4);
    float xd0 = x4.x * mf, xd1 = x4.y * mf, xd2 = x4.z * mf;
    {
        float* xs = sXyz + (p * Kv + u) * 3;
        xs[0] = xd0; xs[1] = xd1; xs[2] = xd2;
    }
    if (t < 240) {
        float v;
        if (t < 24)       v = w1[t];
        else if (t < 32)  v = b1[t - 24];
        else if (t < 160) v = w2[t - 32];
        else if (t < 176) v = b2[t - 160];
        else              v = b_lin[t - 176];
        sNet[t] = v;
    }
    if (t < PPB * 3) { int pp = t / 3, c = t - pp * 3; sNx[pp][c] = sampled[(b * 3 + c) * HWv + n0 + pp]; }
    __syncthreads();

    // ---- P1: weight net, thread = (p,k=u); coords from own registers ----
    {
        const float* W1 = sNet;
        const float* B1 = sNet + 24;
        const float* W2 = sNet + 32;
        const float* B2 = sNet + 160;
        float r0 = xd0 - sNx[p][0];
        float r1 = xd1 - sNx[p][1];
        float r2 = xd2 - sNx[p][2];
        float h[8];
        #pragma unroll
        for (int i = 0; i < 8; ++i)
            h[i] = leaky(W1[i * 3] * r0 + W1[i * 3 + 1] * r1 + W1[i * 3 + 2] * r2 + B1[i]);
        float wk[16];
        #pragma unroll
        for (int f = 0; f < 16; ++f) {
            float v = B2[f];
            #pragma unroll
            for (int i = 0; i < 8; ++i) v += W2[f * 8 + i] * h[i];
            wk[f] = leaky(v) * mf;                   // mask folded into weight
        }
        f32x4* wdst = (f32x4*)(sWt + p * WTSTR + u * 16);
        wdst[0] = (f32x4){wk[0], wk[1], wk[2], wk[3]};
        wdst[1] = (f32x4){wk[4], wk[5], wk[6], wk[7]};
        wdst[2] = (f32x4){wk[8], wk[9], wk[10], wk[11]};
        wdst[3] = (f32x4){wk[12], wk[13], wk[14], wk[15]};
    }
    __syncthreads();

    // ---- P2: aggregation. thread = (p,u); u owns feature channels 4u..4u+3 ----
    float agg[16][4];
    #pragma unroll
    for (int f = 0; f < 16; ++f)
        #pragma unroll
        for (int c = 0; c < 4; ++c) agg[f][c] = 0.f;
    float ax = 0.f, ay = 0.f, az = 0.f;              // xyz-channel agg (f = u role)

    const char* fb = (const char*)feats_bf;
    #pragma unroll
    for (int k = 0; k < Kv; ++k) {
        ushort4 hv = *(const ushort4*)(fb + sRow[p][k] + u * 8);
        float fv0 = bf2f(hv.x), fv1 = bf2f(hv.y), fv2 = bf2f(hv.z), fv3 = bf2f(hv.w);
        const f32x4* wt4 = (const f32x4*)(sWt + p * WTSTR + k * 16);
        f32x4 w0 = wt4[0], w1v = wt4[1], w2v = wt4[2], w3v = wt4[3];
        #pragma unroll
        for (int c = 0; c < 4; ++c) {
            float fv = c == 0 ? fv0 : c == 1 ? fv1 : c == 2 ? fv2 : fv3;
            agg[0][c]  += w0[0] * fv;  agg[1][c]  += w0[1] * fv;
            agg[2][c]  += w0[2] * fv;  agg[3][c]  += w0[3] * fv;
            agg[4][c]  += w1v[0] * fv; agg[5][c]  += w1v[1] * fv;
            agg[6][c]  += w1v[2] * fv; agg[7][c]  += w1v[3] * fv;
            agg[8][c]  += w2v[0] * fv; agg[9][c]  += w2v[1] * fv;
            agg[10][c] += w2v[2] * fv; agg[11][c] += w2v[3] * fv;
            agg[12][c] += w3v[0] * fv; agg[13][c] += w3v[1] * fv;
            agg[14][c] += w3v[2] * fv; agg[15][c] += w3v[3] * fv;
        }
        float wtv = sWt[p * WTSTR + k * 16 + u];
        const float* xs = sXyz + (p * Kv + k) * 3;
        ax += wtv * xs[0]; ay += wtv * xs[1]; az += wtv * xs[2];
    }
    __syncthreads();      // sWt/sXyz dead; sAggH may overlay

    // ---- staged MFMA: two f-halves, each 16 pts x 544 K ----
    int row16 = l & 15;
    int kgrp  = l >> 4;
    f32x4 acc0 = {0.f, 0.f, 0.f, 0.f}, acc1 = {0.f, 0.f, 0.f, 0.f};

    #pragma unroll
    for (int hstage = 0; hstage < 2; ++hstage) {
        // write half hstage: f = hstage*8 + fl
        #pragma unroll
        for (int fl = 0; fl < 8; ++fl) {
            ushort4 hv;
            hv.x = f2bf(agg[hstage * 8 + fl][0]); hv.y = f2bf(agg[hstage * 8 + fl][1]);
            hv.z = f2bf(agg[hstage * 8 + fl][2]); hv.w = f2bf(agg[hstage * 8 + fl][3]);
            *(ushort4*)&sAggH[p * ASTRH + fl * 68 + u * 4] = hv;
        }
        if ((u >> 3) == hstage) {                    // xyz channels for f = u
            ushort4 hx;
            hx.x = f2bf(ax); hx.y = f2bf(ay); hx.z = f2bf(az); hx.w = 0;
            *(ushort4*)&sAggH[p * ASTRH + (u & 7) * 68 + 64] = hx;
        }
        __syncthreads();
        // MFMA over this half: K = 544 = 17 x 32
        const bf16x8* aptr = (const bf16x8*)&sAggH[row16 * ASTRH + kgrp * 8];
        const bf16x8* bptr = (const bf16x8*)(wl_bf + (w * 16 + row16) * KDIM + hstage * KHALF + kgrp * 8);
        if (hstage == 0) {
            #pragma unroll
            for (int kt = 0; kt < 17; ++kt)
                acc0 = __builtin_amdgcn_mfma_f32_16x16x32_bf16(aptr[kt * 4], bptr[kt * 4], acc0, 0, 0, 0);
            __syncthreads();                         // half0 reads done before overwrite
        } else {
            #pragma unroll
            for (int kt = 0; kt < 17; ++kt)
                acc1 = __builtin_amdgcn_mfma_f32_16x16x32_bf16(aptr[kt * 4], bptr[kt * 4], acc1, 0, 0, 0);
        }
    }

    // ---- store ----
    {
        f32x4 acc = acc0 + acc1;
        int o = w * 16 + row16;
        float bias = sNet[176 + o];
        float4 res;
        res.x = leaky(acc[0] + bias);
        res.y = leaky(acc[1] + bias);
        res.z = leaky(acc[2] + bias);
        res.w = leaky(acc[3] + bias);
        *(float4*)(out + (long)(b * COUT + o) * HWv + n0 + kgrp * 4) = res;
    }
}

extern "C" void kernel_launch(void* const* d_in, const int* in_sizes, int n_in,
                              void* d_out, int out_size, void* d_ws, size_t ws_size,
                              hipStream_t stream) {
    const float* xyz      = (const float*)d_in[0];
    const float* features = (const float*)d_in[1];
    const float* sampled  = (const float*)d_in[2];
    const int*   knn_idx  = (const int*)  d_in[3];
    const int*   mask     = (const int*)  d_in[4];
    const float* w1       = (const float*)d_in[5];
    const float* b1       = (const float*)d_in[6];
    const float* w2       = (const float*)d_in[7];
    const float* b2       = (const float*)d_in[8];
    const float* w_lin    = (const float*)d_in[9];
    const float* b_lin    = (const float*)d_in[10];
    float* out = (float*)d_out;

    unsigned short* feats_bf = (unsigned short*)d_ws;
    float* xyz_cl = (float*)((char*)d_ws + (size_t)Bv * HWv * 64 * 2);
    unsigned short* wl_bf = (unsigned short*)((char*)xyz_cl + (size_t)Bv * HWv * 4 * 4);

    transpose_kernel<<<Bv * 560, 256, 0, stream>>>(xyz, features, feats_bf, xyz_cl);
    wl_bf16_kernel<<<(COUT * KDIM + 255) / 256, 256, 0, stream>>>(w_lin, wl_bf);
    pointconv_main<<<Bv * NBLK_PER_B, 256, 0, stream>>>(feats_bf, xyz_cl, wl_bf, knn_idx, mask,
                                                        sampled, w1, b1, w2, b2, b_lin, out);
}

// Round 8
// 219.934 us; speedup vs baseline: 3.5940x; 2.3433x over previous
//
#include <hip/hip_runtime.h>
#include <hip/hip_bf16.h>

#define HWv   35840   // H*W = 160*224
#define NPTS  35840
#define Bv    2
#define Kv    16
#define CP3   67
#define COUT  64
#define PPB   16
#define NBLK_PER_B (NPTS / PPB)   // 2240
#define KDIM  1088    // 16 f * 68 c   (c: 0-63 features, 64-66 xyz, 67 pad)
#define ASTR  1096    // sAgg row stride (bf16 elems); 2192 B, 16B-aligned
#define WTSTR 264     // sWt p-stride in f32

typedef __attribute__((ext_vector_type(4))) float  f32x4;
typedef __attribute__((ext_vector_type(8))) short  bf16x8;

static __device__ __forceinline__ unsigned short f2bf(float f) {
    unsigned int u = __float_as_uint(f);
    unsigned int r = (u + 0x7FFFu + ((u >> 16) & 1u)) >> 16;   // RNE
    return (unsigned short)r;
}
static __device__ __forceinline__ float leaky(float v) { return v >= 0.f ? v : 0.1f * v; }

// ---- kernel 1: channel-last bf16 features [B][HW][64] + f32 xyz [B][HW][4] ----
__global__ __launch_bounds__(256) void transpose_kernel(const float* __restrict__ xyz,
                                                        const float* __restrict__ feat,
                                                        unsigned short* __restrict__ feats_bf,
                                                        float* __restrict__ xyz_cl) {
    __shared__ float tile[68][65];
    int t = threadIdx.x;
    int blk = blockIdx.x;                 // Bv * 560
    int b = blk / 560;
    int hw0 = (blk % 560) * 64;
    int j = t & 63, cq = t >> 6;
    for (int cc = 0; cc < 17; ++cc) {
        int c = cc * 4 + cq;              // 0..67
        float v = 0.f;
        if (c < 64)      v = feat[((long)b * 64 + c) * HWv + hw0 + j];
        else if (c < 67) v = xyz[((long)b * 3 + (c - 64)) * HWv + hw0 + j];
        tile[c][j] = v;
    }
    __syncthreads();
    int r = t >> 2, q = t & 3;
    unsigned short* dst = feats_bf + ((long)b * HWv + hw0 + r) * 64;
    #pragma unroll
    for (int i = q; i < 16; i += 4) {
        ushort4 v;
        v.x = f2bf(tile[i * 4 + 0][r]); v.y = f2bf(tile[i * 4 + 1][r]);
        v.z = f2bf(tile[i * 4 + 2][r]); v.w = f2bf(tile[i * 4 + 3][r]);
        *(ushort4*)(dst + i * 4) = v;
    }
    if (q == 0) {
        float4 x4 = make_float4(tile[64][r], tile[65][r], tile[66][r], 0.f);
        *(float4*)(xyz_cl + ((long)b * HWv + hw0 + r) * 4) = x4;
    }
}

// ---- kernel 1b: w_lin -> bf16 [64][1088], channel-remapped to match sAgg ----
__global__ __launch_bounds__(256) void wl_bf16_kernel(const float* __restrict__ w_lin,
                                                      unsigned short* __restrict__ wl_bf) {
    int e = blockIdx.x * 256 + threadIdx.x;   // 64*1088 = 69632
    if (e >= COUT * KDIM) return;
    int o  = e / KDIM;
    int fc = e - o * KDIM;
    int f  = fc / 68;
    int c  = fc - f * 68;
    float v = 0.f;
    if (c < 64)      v = w_lin[o * (16 * CP3) + f * CP3 + 3 + c];    // feature channels
    else if (c < 67) v = w_lin[o * (16 * CP3) + f * CP3 + (c - 64)]; // xyz channels
    wl_bf[e] = f2bf(v);
}

// ---- kernel 2: fused gather + weightnet + agg + MFMA linear ----
__global__ __launch_bounds__(256, 4) void pointconv_main(
        const unsigned short* __restrict__ feats_bf,
        const float*  __restrict__ xyz_cl,
        const unsigned short* __restrict__ wl_bf,
        const int*    __restrict__ knn_idx,
        const int*    __restrict__ mask,
        const float*  __restrict__ sampled,
        const float*  __restrict__ w1,
        const float*  __restrict__ b1,
        const float*  __restrict__ w2,
        const float*  __restrict__ b2,
        const float*  __restrict__ b_lin,
        float*        __restrict__ out) {
    // lifetime-union region: [sXyz 3072 | sWt 16896] overlaid later by sAgg 35072
    __shared__ __align__(16) char sBuf[PPB * ASTR * 2];     // 35072 B
    __shared__ int   sRow[PPB][Kv];
    __shared__ float sNx[PPB][4];
    __shared__ float sNet[240];        // w1(24) b1(8) w2(128) b2(16) b_lin(64)

    float* sXyz = (float*)sBuf;                      // [p][k][3]
    float* sWt  = (float*)(sBuf + 3072);             // [p][k*16+f], p-stride 264
    unsigned short* sAgg = (unsigned short*)sBuf;    // [p][1096]

    int t = threadIdx.x;
    int blk = blockIdx.x;
    int b = blk / NBLK_PER_B;
    int n0 = (blk % NBLK_PER_B) * PPB;
    int p = t >> 4, u = t & 15;
    int w = t >> 6, l = t & 63;

    // ---- P0: metadata + params ----
    int base = (b * NPTS + n0 + p) * Kv + u;
    int g = knn_idx[base];
    float mf = mask[base] ? 1.f : 0.f;
    int row = b * HWv + g;
    sRow[p][u] = row * 128;                          // byte offset into feats_bf
    float4 x4 = *(const float4*)(xyz_cl + (long)row * 4);
    float xd0 = x4.x * mf, xd1 = x4.y * mf, xd2 = x4.z * mf;
    {
        float* xs = sXyz + (p * Kv + u) * 3;
        xs[0] = xd0; xs[1] = xd1; xs[2] = xd2;
    }
    if (t < 240) {
        float v;
        if (t < 24)       v = w1[t];
        else if (t < 32)  v = b1[t - 24];
        else if (t < 160) v = w2[t - 32];
        else if (t < 176) v = b2[t - 160];
        else              v = b_lin[t - 176];
        sNet[t] = v;
    }
    if (t < PPB * 3) { int pp = t / 3, c = t - pp * 3; sNx[pp][c] = sampled[(b * 3 + c) * HWv + n0 + pp]; }
    __syncthreads();

    // ---- P1: weight net, thread = (p,k=u); coords from own registers ----
    {
        const float* W1 = sNet;
        const float* B1 = sNet + 24;
        const float* W2 = sNet + 32;
        const float* B2 = sNet + 160;
        float r0 = xd0 - sNx[p][0];
        float r1 = xd1 - sNx[p][1];
        float r2 = xd2 - sNx[p][2];
        float h[8];
        #pragma unroll
        for (int i = 0; i < 8; ++i)
            h[i] = leaky(W1[i * 3] * r0 + W1[i * 3 + 1] * r1 + W1[i * 3 + 2] * r2 + B1[i]);
        float wk[16];
        #pragma unroll
        for (int f = 0; f < 16; ++f) {
            float v = B2[f];
            #pragma unroll
            for (int i = 0; i < 8; ++i) v += W2[f * 8 + i] * h[i];
            wk[f] = leaky(v) * mf;                   // mask folded into weight
        }
        f32x4* wdst = (f32x4*)(sWt + p * WTSTR + u * 16);
        wdst[0] = (f32x4){wk[0], wk[1], wk[2], wk[3]};
        wdst[1] = (f32x4){wk[4], wk[5], wk[6], wk[7]};
        wdst[2] = (f32x4){wk[8], wk[9], wk[10], wk[11]};
        wdst[3] = (f32x4){wk[12], wk[13], wk[14], wk[15]};
    }
    __syncthreads();

    // ---- P2: aggregation. thread = (p,u); u owns feature channels 4u..4u+3 ----
    // Prefetch ALL 16 gather rows into named registers (static indexing only).
    const char* fb = (const char*)feats_bf;
    #define LOADK(K) uint2 v##K = *(const uint2*)(fb + sRow[p][K] + (u << 3))
    LOADK(0);  LOADK(1);  LOADK(2);  LOADK(3);
    LOADK(4);  LOADK(5);  LOADK(6);  LOADK(7);
    LOADK(8);  LOADK(9);  LOADK(10); LOADK(11);
    LOADK(12); LOADK(13); LOADK(14); LOADK(15);
    #undef LOADK

    float agg[16][4];
    #pragma unroll
    for (int f = 0; f < 16; ++f)
        #pragma unroll
        for (int c = 0; c < 4; ++c) agg[f][c] = 0.f;
    float ax = 0.f, ay = 0.f, az = 0.f;              // xyz-channel agg (f = u role)

    #define AGGSTEP(K, V) do {                                                      \
        float fv0 = __uint_as_float((V).x << 16);                                   \
        float fv1 = __uint_as_float((V).x & 0xffff0000u);                           \
        float fv2 = __uint_as_float((V).y << 16);                                   \
        float fv3 = __uint_as_float((V).y & 0xffff0000u);                           \
        const f32x4* wt4 = (const f32x4*)(sWt + p * WTSTR + (K) * 16);              \
        f32x4 w0 = wt4[0], w1v = wt4[1], w2v = wt4[2], w3v = wt4[3];                \
        _Pragma("unroll")                                                           \
        for (int c = 0; c < 4; ++c) {                                               \
            float fv = c == 0 ? fv0 : c == 1 ? fv1 : c == 2 ? fv2 : fv3;            \
            agg[0][c]  += w0[0] * fv;  agg[1][c]  += w0[1] * fv;                    \
            agg[2][c]  += w0[2] * fv;  agg[3][c]  += w0[3] * fv;                    \
            agg[4][c]  += w1v[0] * fv; agg[5][c]  += w1v[1] * fv;                   \
            agg[6][c]  += w1v[2] * fv; agg[7][c]  += w1v[3] * fv;                   \
            agg[8][c]  += w2v[0] * fv; agg[9][c]  += w2v[1] * fv;                   \
            agg[10][c] += w2v[2] * fv; agg[11][c] += w2v[3] * fv;                   \
            agg[12][c] += w3v[0] * fv; agg[13][c] += w3v[1] * fv;                   \
            agg[14][c] += w3v[2] * fv; agg[15][c] += w3v[3] * fv;                   \
        }                                                                           \
        float wtv = sWt[p * WTSTR + (K) * 16 + u];                                  \
        const float* xs = sXyz + (p * Kv + (K)) * 3;                                \
        ax += wtv * xs[0]; ay += wtv * xs[1]; az += wtv * xs[2];                    \
    } while (0)

    AGGSTEP(0, v0);   AGGSTEP(1, v1);   AGGSTEP(2, v2);   AGGSTEP(3, v3);
    AGGSTEP(4, v4);   AGGSTEP(5, v5);   AGGSTEP(6, v6);   AGGSTEP(7, v7);
    AGGSTEP(8, v8);   AGGSTEP(9, v9);   AGGSTEP(10, v10); AGGSTEP(11, v11);
    AGGSTEP(12, v12); AGGSTEP(13, v13); AGGSTEP(14, v14); AGGSTEP(15, v15);
    #undef AGGSTEP
    __syncthreads();      // all waves done reading sWt/sXyz; sAgg may overlay

    // ---- write agg -> bf16 LDS ----
    {
        #pragma unroll
        for (int f = 0; f < 16; ++f) {
            ushort4 hv;
            hv.x = f2bf(agg[f][0]); hv.y = f2bf(agg[f][1]);
            hv.z = f2bf(agg[f][2]); hv.w = f2bf(agg[f][3]);
            *(ushort4*)&sAgg[p * ASTR + f * 68 + u * 4] = hv;
        }
        ushort4 hx;
        hx.x = f2bf(ax); hx.y = f2bf(ay); hx.z = f2bf(az); hx.w = 0;
        *(ushort4*)&sAgg[p * ASTR + u * 68 + 64] = hx;   // thread acts as f=u here
    }
    __syncthreads();

    // ---- P3: MFMA  out[16 pts][64 outs] = sAgg[16][1088] x wl_bf[64][1088]^T ----
    {
        int row16 = l & 15;
        int kgrp  = l >> 4;
        const bf16x8* aptr = (const bf16x8*)&sAgg[row16 * ASTR + kgrp * 8];
        const bf16x8* bptr = (const bf16x8*)(wl_bf + (w * 16 + row16) * KDIM + kgrp * 8);
        f32x4 acc0 = {0.f, 0.f, 0.f, 0.f}, acc1 = {0.f, 0.f, 0.f, 0.f};
        #pragma unroll
        for (int kt = 0; kt < 17; ++kt)
            acc0 = __builtin_amdgcn_mfma_f32_16x16x32_bf16(aptr[kt * 4], bptr[kt * 4], acc0, 0, 0, 0);
        #pragma unroll
        for (int kt = 17; kt < 34; ++kt)
            acc1 = __builtin_amdgcn_mfma_f32_16x16x32_bf16(aptr[kt * 4], bptr[kt * 4], acc1, 0, 0, 0);
        f32x4 acc = acc0 + acc1;
        int o = w * 16 + row16;
        float bias = sNet[176 + o];
        float4 res;
        res.x = leaky(acc[0] + bias);
        res.y = leaky(acc[1] + bias);
        res.z = leaky(acc[2] + bias);
        res.w = leaky(acc[3] + bias);
        *(float4*)(out + (long)(b * COUT + o) * HWv + n0 + kgrp * 4) = res;
    }
}

extern "C" void kernel_launch(void* const* d_in, const int* in_sizes, int n_in,
                              void* d_out, int out_size, void* d_ws, size_t ws_size,
                              hipStream_t stream) {
    const float* xyz      = (const float*)d_in[0];
    const float* features = (const float*)d_in[1];
    const float* sampled  = (const float*)d_in[2];
    const int*   knn_idx  = (const int*)  d_in[3];
    const int*   mask     = (const int*)  d_in[4];
    const float* w1       = (const float*)d_in[5];
    const float* b1       = (const float*)d_in[6];
    const float* w2       = (const float*)d_in[7];
    const float* b2       = (const float*)d_in[8];
    const float* w_lin    = (const float*)d_in[9];
    const float* b_lin    = (const float*)d_in[10];
    float* out = (float*)d_out;

    unsigned short* feats_bf = (unsigned short*)d_ws;
    float* xyz_cl = (float*)((char*)d_ws + (size_t)Bv * HWv * 64 * 2);
    unsigned short* wl_bf = (unsigned short*)((char*)xyz_cl + (size_t)Bv * HWv * 4 * 4);

    transpose_kernel<<<Bv * 560, 256, 0, stream>>>(xyz, features, feats_bf, xyz_cl);
    wl_bf16_kernel<<<(COUT * KDIM + 255) / 256, 256, 0, stream>>>(w_lin, wl_bf);
    pointconv_main<<<Bv * NBLK_PER_B, 256, 0, stream>>>(feats_bf, xyz_cl, wl_bf, knn_idx, mask,
                                                        sampled, w1, b1, w2, b2, b_lin, out);
}

// Round 9
// 219.197 us; speedup vs baseline: 3.6061x; 1.0034x over previous
//
#include <hip/hip_runtime.h>
#include <hip/hip_bf16.h>

#define HWv   35840   // H*W = 160*224
#define NPTS  35840
#define Bv    2
#define Kv    16
#define CP3   67
#define COUT  64
#define PPB   16
#define NBLK_PER_B (NPTS / PPB)   // 2240
#define KDIM  1088    // 16 f * 68 c   (c: 0-63 features, 64-66 xyz, 67 pad)
#define ASTR  1096    // sAgg row stride (bf16 elems); 2192 B, 16B-aligned
#define WTSTR 264     // sWt p-stride in f32

typedef __attribute__((ext_vector_type(4))) float  f32x4;
typedef __attribute__((ext_vector_type(8))) short  bf16x8;

static __device__ __forceinline__ unsigned short f2bf(float f) {
    unsigned int u = __float_as_uint(f);
    unsigned int r = (u + 0x7FFFu + ((u >> 16) & 1u)) >> 16;   // RNE
    return (unsigned short)r;
}
static __device__ __forceinline__ float leaky(float v) { return v >= 0.f ? v : 0.1f * v; }

// ---- kernel 1: channel-last bf16 features [B][HW][64] + f32 xyz [B][HW][4] ----
__global__ __launch_bounds__(256) void transpose_kernel(const float* __restrict__ xyz,
                                                        const float* __restrict__ feat,
                                                        unsigned short* __restrict__ feats_bf,
                                                        float* __restrict__ xyz_cl) {
    __shared__ float tile[68][65];
    int t = threadIdx.x;
    int blk = blockIdx.x;                 // Bv * 560
    int b = blk / 560;
    int hw0 = (blk % 560) * 64;
    int j = t & 63, cq = t >> 6;
    for (int cc = 0; cc < 17; ++cc) {
        int c = cc * 4 + cq;              // 0..67
        float v = 0.f;
        if (c < 64)      v = feat[((long)b * 64 + c) * HWv + hw0 + j];
        else if (c < 67) v = xyz[((long)b * 3 + (c - 64)) * HWv + hw0 + j];
        tile[c][j] = v;
    }
    __syncthreads();
    int r = t >> 2, q = t & 3;
    unsigned short* dst = feats_bf + ((long)b * HWv + hw0 + r) * 64;
    #pragma unroll
    for (int i = q; i < 16; i += 4) {
        ushort4 v;
        v.x = f2bf(tile[i * 4 + 0][r]); v.y = f2bf(tile[i * 4 + 1][r]);
        v.z = f2bf(tile[i * 4 + 2][r]); v.w = f2bf(tile[i * 4 + 3][r]);
        *(ushort4*)(dst + i * 4) = v;
    }
    if (q == 0) {
        float4 x4 = make_float4(tile[64][r], tile[65][r], tile[66][r], 0.f);
        *(float4*)(xyz_cl + ((long)b * HWv + hw0 + r) * 4) = x4;
    }
}

// ---- kernel 1b: w_lin -> bf16 [64][1088], channel-remapped to match sAgg ----
__global__ __launch_bounds__(256) void wl_bf16_kernel(const float* __restrict__ w_lin,
                                                      unsigned short* __restrict__ wl_bf) {
    int e = blockIdx.x * 256 + threadIdx.x;   // 64*1088 = 69632
    if (e >= COUT * KDIM) return;
    int o  = e / KDIM;
    int fc = e - o * KDIM;
    int f  = fc / 68;
    int c  = fc - f * 68;
    float v = 0.f;
    if (c < 64)      v = w_lin[o * (16 * CP3) + f * CP3 + 3 + c];    // feature channels
    else if (c < 67) v = w_lin[o * (16 * CP3) + f * CP3 + (c - 64)]; // xyz channels
    wl_bf[e] = f2bf(v);
}

// ---- kernel 2: fused gather + weightnet + agg + MFMA linear ----
// amdgpu_waves_per_eu(4,4): pin allocator occupancy target to 4 waves/EU
// (= the LDS limit anyway) so the VGPR budget is 128, not 64 — R4-R8 all
// spilled because the default target of 8/EU caps live regs at 64.
__global__ __launch_bounds__(256) __attribute__((amdgpu_waves_per_eu(4, 4)))
void pointconv_main(
        const unsigned short* __restrict__ feats_bf,
        const float*  __restrict__ xyz_cl,
        const unsigned short* __restrict__ wl_bf,
        const int*    __restrict__ knn_idx,
        const int*    __restrict__ mask,
        const float*  __restrict__ sampled,
        const float*  __restrict__ w1,
        const float*  __restrict__ b1,
        const float*  __restrict__ w2,
        const float*  __restrict__ b2,
        const float*  __restrict__ b_lin,
        float*        __restrict__ out) {
    // lifetime-union region: [sXyz 3072 | sWt 16896] overlaid later by sAgg 35072
    __shared__ __align__(16) char sBuf[PPB * ASTR * 2];     // 35072 B
    __shared__ int   sRow[PPB][Kv];
    __shared__ float sNx[PPB][4];
    __shared__ float sNet[240];        // w1(24) b1(8) w2(128) b2(16) b_lin(64)

    float* sXyz = (float*)sBuf;                      // [p][k][3]
    float* sWt  = (float*)(sBuf + 3072);             // [p][k*16+f], p-stride 264
    unsigned short* sAgg = (unsigned short*)sBuf;    // [p][1096]

    int t = threadIdx.x;
    int blk = blockIdx.x;
    int b = blk / NBLK_PER_B;
    int n0 = (blk % NBLK_PER_B) * PPB;
    int p = t >> 4, u = t & 15;
    int w = t >> 6, l = t & 63;

    // ---- P0: metadata + params ----
    int base = (b * NPTS + n0 + p) * Kv + u;
    int g = knn_idx[base];
    float mf = mask[base] ? 1.f : 0.f;
    int row = b * HWv + g;
    sRow[p][u] = row * 128;                          // byte offset into feats_bf
    float4 x4 = *(const float4*)(xyz_cl + (long)row * 4);
    float xd0 = x4.x * mf, xd1 = x4.y * mf, xd2 = x4.z * mf;
    {
        float* xs = sXyz + (p * Kv + u) * 3;
        xs[0] = xd0; xs[1] = xd1; xs[2] = xd2;
    }
    if (t < 240) {
        float v;
        if (t < 24)       v = w1[t];
        else if (t < 32)  v = b1[t - 24];
        else if (t < 160) v = w2[t - 32];
        else if (t < 176) v = b2[t - 160];
        else              v = b_lin[t - 176];
        sNet[t] = v;
    }
    if (t < PPB * 3) { int pp = t / 3, c = t - pp * 3; sNx[pp][c] = sampled[(b * 3 + c) * HWv + n0 + pp]; }
    __syncthreads();

    // ---- P1: weight net, thread = (p,k=u); coords from own registers ----
    {
        const float* W1 = sNet;
        const float* B1 = sNet + 24;
        const float* W2 = sNet + 32;
        const float* B2 = sNet + 160;
        float r0 = xd0 - sNx[p][0];
        float r1 = xd1 - sNx[p][1];
        float r2 = xd2 - sNx[p][2];
        float h[8];
        #pragma unroll
        for (int i = 0; i < 8; ++i)
            h[i] = leaky(W1[i * 3] * r0 + W1[i * 3 + 1] * r1 + W1[i * 3 + 2] * r2 + B1[i]);
        float wk[16];
        #pragma unroll
        for (int f = 0; f < 16; ++f) {
            float v = B2[f];
            #pragma unroll
            for (int i = 0; i < 8; ++i) v += W2[f * 8 + i] * h[i];
            wk[f] = leaky(v) * mf;                   // mask folded into weight
        }
        f32x4* wdst = (f32x4*)(sWt + p * WTSTR + u * 16);
        wdst[0] = (f32x4){wk[0], wk[1], wk[2], wk[3]};
        wdst[1] = (f32x4){wk[4], wk[5], wk[6], wk[7]};
        wdst[2] = (f32x4){wk[8], wk[9], wk[10], wk[11]};
        wdst[3] = (f32x4){wk[12], wk[13], wk[14], wk[15]};
    }
    __syncthreads();

    // ---- P2: aggregation. thread = (p,u); u owns feature channels 4u..4u+3 ----
    const char* fb = (const char*)feats_bf;
    float agg[16][4];
    #pragma unroll
    for (int f = 0; f < 16; ++f)
        #pragma unroll
        for (int c = 0; c < 4; ++c) agg[f][c] = 0.f;
    float ax = 0.f, ay = 0.f, az = 0.f;              // xyz-channel agg (f = u role)

    #define LOADK(K) uint2 v##K = *(const uint2*)(fb + sRow[p][K] + (u << 3))
    #define AGGSTEP(K, V) do {                                                      \
        float fv0 = __uint_as_float((V).x << 16);                                   \
        float fv1 = __uint_as_float((V).x & 0xffff0000u);                           \
        float fv2 = __uint_as_float((V).y << 16);                                   \
        float fv3 = __uint_as_float((V).y & 0xffff0000u);                           \
        const f32x4* wt4 = (const f32x4*)(sWt + p * WTSTR + (K) * 16);              \
        f32x4 w0 = wt4[0], w1v = wt4[1], w2v = wt4[2], w3v = wt4[3];                \
        _Pragma("unroll")                                                           \
        for (int c = 0; c < 4; ++c) {                                               \
            float fv = c == 0 ? fv0 : c == 1 ? fv1 : c == 2 ? fv2 : fv3;            \
            agg[0][c]  += w0[0] * fv;  agg[1][c]  += w0[1] * fv;                    \
            agg[2][c]  += w0[2] * fv;  agg[3][c]  += w0[3] * fv;                    \
            agg[4][c]  += w1v[0] * fv; agg[5][c]  += w1v[1] * fv;                   \
            agg[6][c]  += w1v[2] * fv; agg[7][c]  += w1v[3] * fv;                   \
            agg[8][c]  += w2v[0] * fv; agg[9][c]  += w2v[1] * fv;                   \
            agg[10][c] += w2v[2] * fv; agg[11][c] += w2v[3] * fv;                   \
            agg[12][c] += w3v[0] * fv; agg[13][c] += w3v[1] * fv;                   \
            agg[14][c] += w3v[2] * fv; agg[15][c] += w3v[3] * fv;                   \
        }                                                                           \
        float wtv = sWt[p * WTSTR + (K) * 16 + u];                                  \
        const float* xs = sXyz + (p * Kv + (K)) * 3;                                \
        ax += wtv * xs[0]; ay += wtv * xs[1]; az += wtv * xs[2];                    \
    } while (0)

    // 8-deep staggered prefetch: peak live pressure ~100 VGPR < 128 budget
    LOADK(0);  LOADK(1);  LOADK(2);  LOADK(3);
    LOADK(4);  LOADK(5);  LOADK(6);  LOADK(7);
    AGGSTEP(0, v0);   AGGSTEP(1, v1);   AGGSTEP(2, v2);   AGGSTEP(3, v3);
    LOADK(8);  LOADK(9);  LOADK(10); LOADK(11);
    AGGSTEP(4, v4);   AGGSTEP(5, v5);   AGGSTEP(6, v6);   AGGSTEP(7, v7);
    LOADK(12); LOADK(13); LOADK(14); LOADK(15);
    AGGSTEP(8, v8);   AGGSTEP(9, v9);   AGGSTEP(10, v10); AGGSTEP(11, v11);
    AGGSTEP(12, v12); AGGSTEP(13, v13); AGGSTEP(14, v14); AGGSTEP(15, v15);
    #undef LOADK
    #undef AGGSTEP
    __syncthreads();      // all waves done reading sWt/sXyz; sAgg may overlay

    // ---- write agg -> bf16 LDS ----
    {
        #pragma unroll
        for (int f = 0; f < 16; ++f) {
            ushort4 hv;
            hv.x = f2bf(agg[f][0]); hv.y = f2bf(agg[f][1]);
            hv.z = f2bf(agg[f][2]); hv.w = f2bf(agg[f][3]);
            *(ushort4*)&sAgg[p * ASTR + f * 68 + u * 4] = hv;
        }
        ushort4 hx;
        hx.x = f2bf(ax); hx.y = f2bf(ay); hx.z = f2bf(az); hx.w = 0;
        *(ushort4*)&sAgg[p * ASTR + u * 68 + 64] = hx;   // thread acts as f=u here
    }
    __syncthreads();

    // ---- P3: MFMA  out[16 pts][64 outs] = sAgg[16][1088] x wl_bf[64][1088]^T ----
    {
        int row16 = l & 15;
        int kgrp  = l >> 4;
        const bf16x8* aptr = (const bf16x8*)&sAgg[row16 * ASTR + kgrp * 8];
        const bf16x8* bptr = (const bf16x8*)(wl_bf + (w * 16 + row16) * KDIM + kgrp * 8);
        f32x4 acc0 = {0.f, 0.f, 0.f, 0.f}, acc1 = {0.f, 0.f, 0.f, 0.f};
        #pragma unroll
        for (int kt = 0; kt < 17; ++kt)
            acc0 = __builtin_amdgcn_mfma_f32_16x16x32_bf16(aptr[kt * 4], bptr[kt * 4], acc0, 0, 0, 0);
        #pragma unroll
        for (int kt = 17; kt < 34; ++kt)
            acc1 = __builtin_amdgcn_mfma_f32_16x16x32_bf16(aptr[kt * 4], bptr[kt * 4], acc1, 0, 0, 0);
        f32x4 acc = acc0 + acc1;
        int o = w * 16 + row16;
        float bias = sNet[176 + o];
        float4 res;
        res.x = leaky(acc[0] + bias);
        res.y = leaky(acc[1] + bias);
        res.z = leaky(acc[2] + bias);
        res.w = leaky(acc[3] + bias);
        *(float4*)(out + (long)(b * COUT + o) * HWv + n0 + kgrp * 4) = res;
    }
}

extern "C" void kernel_launch(void* const* d_in, const int* in_sizes, int n_in,
                              void* d_out, int out_size, void* d_ws, size_t ws_size,
                              hipStream_t stream) {
    const float* xyz      = (const float*)d_in[0];
    const float* features = (const float*)d_in[1];
    const float* sampled  = (const float*)d_in[2];
    const int*   knn_idx  = (const int*)  d_in[3];
    const int*   mask     = (const int*)  d_in[4];
    const float* w1       = (const float*)d_in[5];
    const float* b1       = (const float*)d_in[6];
    const float* w2       = (const float*)d_in[7];
    const float* b2       = (const float*)d_in[8];
    const float* w_lin    = (const float*)d_in[9];
    const float* b_lin    = (const float*)d_in[10];
    float* out = (float*)d_out;

    unsigned short* feats_bf = (unsigned short*)d_ws;
    float* xyz_cl = (float*)((char*)d_ws + (size_t)Bv * HWv * 64 * 2);
    unsigned short* wl_bf = (unsigned short*)((char*)xyz_cl + (size_t)Bv * HWv * 4 * 4);

    transpose_kernel<<<Bv * 560, 256, 0, stream>>>(xyz, features, feats_bf, xyz_cl);
    wl_bf16_kernel<<<(COUT * KDIM + 255) / 256, 256, 0, stream>>>(w_lin, wl_bf);
    pointconv_main<<<Bv * NBLK_PER_B, 256, 0, stream>>>(feats_bf, xyz_cl, wl_bf, knn_idx, mask,
                                                        sampled, w1, b1, w2, b2, b_lin, out);
}

// Round 10
// 145.741 us; speedup vs baseline: 5.4236x; 1.5040x over previous
//
#include <hip/hip_runtime.h>
#include <hip/hip_bf16.h>

#define HWv   35840   // H*W = 160*224
#define NPTS  35840
#define Bv    2
#define Kv    16
#define CP3   67
#define COUT  64
#define PPB   16
#define NBLK_PER_B (NPTS / PPB)   // 2240
#define KDIM  1088    // 16 f * 68 c   (c: 0-63 features, 64-66 xyz, 67 pad)
#define ASTR  1096    // sAgg row stride (bf16 elems); 2192 B, 16B-aligned
#define WTSTR 264     // sWt p-stride in f32

typedef __attribute__((ext_vector_type(4))) float  f32x4;
typedef __attribute__((ext_vector_type(8))) short  bf16x8;
typedef const unsigned int __attribute__((address_space(1)))* gas1_t;
typedef unsigned int       __attribute__((address_space(3)))* las3_t;

static __device__ __forceinline__ unsigned short f2bf(float f) {
    unsigned int u = __float_as_uint(f);
    unsigned int r = (u + 0x7FFFu + ((u >> 16) & 1u)) >> 16;   // RNE
    return (unsigned short)r;
}
static __device__ __forceinline__ float bf2f(unsigned short s) {
    return __uint_as_float((unsigned int)s << 16);
}
static __device__ __forceinline__ float leaky(float v) { return v >= 0.f ? v : 0.1f * v; }

// ---- kernel 1: channel-last bf16 features [B][HW][64] + f32 xyz [B][HW][4] ----
__global__ __launch_bounds__(256) void transpose_kernel(const float* __restrict__ xyz,
                                                        const float* __restrict__ feat,
                                                        unsigned short* __restrict__ feats_bf,
                                                        float* __restrict__ xyz_cl) {
    __shared__ float tile[68][65];
    int t = threadIdx.x;
    int blk = blockIdx.x;                 // Bv * 560
    int b = blk / 560;
    int hw0 = (blk % 560) * 64;
    int j = t & 63, cq = t >> 6;
    for (int cc = 0; cc < 17; ++cc) {
        int c = cc * 4 + cq;              // 0..67
        float v = 0.f;
        if (c < 64)      v = feat[((long)b * 64 + c) * HWv + hw0 + j];
        else if (c < 67) v = xyz[((long)b * 3 + (c - 64)) * HWv + hw0 + j];
        tile[c][j] = v;
    }
    __syncthreads();
    int r = t >> 2, q = t & 3;
    unsigned short* dst = feats_bf + ((long)b * HWv + hw0 + r) * 64;
    #pragma unroll
    for (int i = q; i < 16; i += 4) {
        ushort4 v;
        v.x = f2bf(tile[i * 4 + 0][r]); v.y = f2bf(tile[i * 4 + 1][r]);
        v.z = f2bf(tile[i * 4 + 2][r]); v.w = f2bf(tile[i * 4 + 3][r]);
        *(ushort4*)(dst + i * 4) = v;
    }
    if (q == 0) {
        float4 x4 = make_float4(tile[64][r], tile[65][r], tile[66][r], 0.f);
        *(float4*)(xyz_cl + ((long)b * HWv + hw0 + r) * 4) = x4;
    }
}

// ---- kernel 1b: w_lin -> bf16 [64][1088], channel-remapped to match sAgg ----
__global__ __launch_bounds__(256) void wl_bf16_kernel(const float* __restrict__ w_lin,
                                                      unsigned short* __restrict__ wl_bf) {
    int e = blockIdx.x * 256 + threadIdx.x;   // 64*1088 = 69632
    if (e >= COUT * KDIM) return;
    int o  = e / KDIM;
    int fc = e - o * KDIM;
    int f  = fc / 68;
    int c  = fc - f * 68;
    float v = 0.f;
    if (c < 64)      v = w_lin[o * (16 * CP3) + f * CP3 + 3 + c];    // feature channels
    else if (c < 67) v = w_lin[o * (16 * CP3) + f * CP3 + (c - 64)]; // xyz channels
    wl_bf[e] = f2bf(v);
}

// ---- kernel 2: fused gather(DMA->LDS) + weightnet + agg + MFMA linear ----
// 64-VGPR discipline: no register prefetch arrays (R4-R9 all spilled).
// Gather latency hidden via global_load_lds issued in P0, consumed after P1.
__global__ __launch_bounds__(256) void pointconv_main(
        const unsigned short* __restrict__ feats_bf,
        const float*  __restrict__ xyz_cl,
        const unsigned short* __restrict__ wl_bf,
        const int*    __restrict__ knn_idx,
        const int*    __restrict__ mask,
        const float*  __restrict__ sampled,
        const float*  __restrict__ w1,
        const float*  __restrict__ b1,
        const float*  __restrict__ w2,
        const float*  __restrict__ b2,
        const float*  __restrict__ b_lin,
        float*        __restrict__ out) {
    // layout: [sFeat 32768 | sWt 16896] ; sAgg(35072) overlays sFeat+sWt after P2
    __shared__ __align__(16) char sBuf[49664];
    __shared__ float sNx[PPB][4];
    __shared__ float sNet[240];        // w1(24) b1(8) w2(128) b2(16) b_lin(64)

    float* sWt = (float*)(sBuf + 32768);             // [p][k*16+f], p-stride 264
    unsigned short* sAgg = (unsigned short*)sBuf;    // [p][1096]

    int t = threadIdx.x;
    int blk = blockIdx.x;
    int b = blk / NBLK_PER_B;
    int n0 = (blk % NBLK_PER_B) * PPB;
    int p = t >> 4, u = t & 15;
    int w = t >> 6, l = t & 63;

    // ---- P0: metadata + params (all wave-local / identical-value) ----
    int base = (b * NPTS + n0 + p) * Kv + u;
    int g = knn_idx[base];
    float mf = mask[base] ? 1.f : 0.f;
    int row = b * HWv + g;
    int rb = row << 7;                               // byte offset into feats_bf
    float4 x4 = *(const float4*)(xyz_cl + (long)row * 4);
    float xd0 = x4.x * mf, xd1 = x4.y * mf, xd2 = x4.z * mf;  // masked neighbor xyz (lane-resident)

    // per-wave redundant param staging (identical values from every wave)
    #pragma unroll
    for (int i0 = 0; i0 < 4; ++i0) {
        int i = i0 * 64 + l;
        if (i < 240) {
            float v;
            if (i < 24)       v = w1[i];
            else if (i < 32)  v = b1[i - 24];
            else if (i < 160) v = w2[i - 32];
            else if (i < 176) v = b2[i - 160];
            else              v = b_lin[i - 176];
            sNet[i] = v;
        }
    }
    if (l < 12) {                                    // this wave's 4 points
        int pp = (w << 2) + (l / 3), c = l - (l / 3) * 3;
        sNx[pp][c] = sampled[(b * 3 + c) * HWv + n0 + pp];
    }

    // ---- issue async gather: 8 DMA calls stage this wave's 64 rows (8 KB) ----
    // lane l owns row (p_local=l>>4, k=l&15) at region offset l*128; call j
    // stages rows j*8..j*8+7: lane i loads 16B chunk (i&7) of row j*8+(i>>3).
    {
        const char* fbc = (const char*)feats_bf;
        #pragma unroll
        for (int j = 0; j < 8; ++j) {
            int rbj = __shfl(rb, (j << 3) + (l >> 3), 64);
            __builtin_amdgcn_global_load_lds(
                (gas1_t)(fbc + rbj + ((l & 7) << 4)),
                (las3_t)(sBuf + (w << 13) + (j << 10) + (l << 4)), 16, 0, 0);
        }
    }

    // ---- P1: weight net (hides DMA latency), thread = (p,k=u) ----
    {
        const float* W1 = sNet;
        const float* B1 = sNet + 24;
        const float* W2 = sNet + 32;
        const float* B2 = sNet + 160;
        float r0 = xd0 - sNx[p][0];
        float r1 = xd1 - sNx[p][1];
        float r2 = xd2 - sNx[p][2];
        float h[8];
        #pragma unroll
        for (int i = 0; i < 8; ++i)
            h[i] = leaky(W1[i * 3] * r0 + W1[i * 3 + 1] * r1 + W1[i * 3 + 2] * r2 + B1[i]);
        float wk[16];
        #pragma unroll
        for (int f = 0; f < 16; ++f) {
            float v = B2[f];
            #pragma unroll
            for (int i = 0; i < 8; ++i) v += W2[f * 8 + i] * h[i];
            wk[f] = leaky(v) * mf;                   // mask folded into weight
        }
        f32x4* wdst = (f32x4*)(sWt + p * WTSTR + u * 16);
        wdst[0] = (f32x4){wk[0], wk[1], wk[2], wk[3]};
        wdst[1] = (f32x4){wk[4], wk[5], wk[6], wk[7]};
        wdst[2] = (f32x4){wk[8], wk[9], wk[10], wk[11]};
        wdst[3] = (f32x4){wk[12], wk[13], wk[14], wk[15]};
    }

    // wave-local: this wave only consumes what IT staged and wrote
    asm volatile("s_waitcnt vmcnt(0)" ::: "memory");
    __builtin_amdgcn_sched_barrier(0);

    // ---- P2: aggregation from LDS. thread = (p,u); u owns channels 4u..4u+3 ----
    float agg[16][4];
    #pragma unroll
    for (int f = 0; f < 16; ++f)
        #pragma unroll
        for (int c = 0; c < 4; ++c) agg[f][c] = 0.f;
    float ax = 0.f, ay = 0.f, az = 0.f;              // xyz-channel agg (f = u role)

    const char* sFeatW = sBuf + (w << 13);           // this wave's 64 staged rows
    #pragma unroll
    for (int k = 0; k < Kv; ++k) {
        ushort4 hv = *(const ushort4*)(sFeatW + (((p & 3) << 4) + k) * 128 + (u << 3));
        float fv0 = bf2f(hv.x), fv1 = bf2f(hv.y), fv2 = bf2f(hv.z), fv3 = bf2f(hv.w);
        const f32x4* wt4 = (const f32x4*)(sWt + p * WTSTR + k * 16);
        f32x4 w0 = wt4[0], w1v = wt4[1], w2v = wt4[2], w3v = wt4[3];
        #pragma unroll
        for (int c = 0; c < 4; ++c) {
            float fv = c == 0 ? fv0 : c == 1 ? fv1 : c == 2 ? fv2 : fv3;
            agg[0][c]  += w0[0] * fv;  agg[1][c]  += w0[1] * fv;
            agg[2][c]  += w0[2] * fv;  agg[3][c]  += w0[3] * fv;
            agg[4][c]  += w1v[0] * fv; agg[5][c]  += w1v[1] * fv;
            agg[6][c]  += w1v[2] * fv; agg[7][c]  += w1v[3] * fv;
            agg[8][c]  += w2v[0] * fv; agg[9][c]  += w2v[1] * fv;
            agg[10][c] += w2v[2] * fv; agg[11][c] += w2v[3] * fv;
            agg[12][c] += w3v[0] * fv; agg[13][c] += w3v[1] * fv;
            agg[14][c] += w3v[2] * fv; agg[15][c] += w3v[3] * fv;
        }
        // xyz channels: weight from LDS, neighbor xyz from owner lane's registers
        float wtv = sWt[p * WTSTR + k * 16 + u];
        int srcl = ((p & 3) << 4) + k;
        ax += wtv * __shfl(xd0, srcl, 64);
        ay += wtv * __shfl(xd1, srcl, 64);
        az += wtv * __shfl(xd2, srcl, 64);
    }
    __syncthreads();      // all waves done reading sFeat/sWt; sAgg may overlay

    // ---- write agg -> bf16 LDS ----
    {
        #pragma unroll
        for (int f = 0; f < 16; ++f) {
            ushort4 hv;
            hv.x = f2bf(agg[f][0]); hv.y = f2bf(agg[f][1]);
            hv.z = f2bf(agg[f][2]); hv.w = f2bf(agg[f][3]);
            *(ushort4*)&sAgg[p * ASTR + f * 68 + u * 4] = hv;
        }
        ushort4 hx;
        hx.x = f2bf(ax); hx.y = f2bf(ay); hx.z = f2bf(az); hx.w = 0;
        *(ushort4*)&sAgg[p * ASTR + u * 68 + 64] = hx;   // thread acts as f=u here
    }
    __syncthreads();

    // ---- P3: MFMA  out[16 pts][64 outs] = sAgg[16][1088] x wl_bf[64][1088]^T ----
    {
        int row16 = l & 15;
        int kgrp  = l >> 4;
        const bf16x8* aptr = (const bf16x8*)&sAgg[row16 * ASTR + kgrp * 8];
        const bf16x8* bptr = (const bf16x8*)(wl_bf + (w * 16 + row16) * KDIM + kgrp * 8);
        f32x4 acc0 = {0.f, 0.f, 0.f, 0.f}, acc1 = {0.f, 0.f, 0.f, 0.f};
        #pragma unroll
        for (int kt = 0; kt < 17; ++kt)
            acc0 = __builtin_amdgcn_mfma_f32_16x16x32_bf16(aptr[kt * 4], bptr[kt * 4], acc0, 0, 0, 0);
        #pragma unroll
        for (int kt = 17; kt < 34; ++kt)
            acc1 = __builtin_amdgcn_mfma_f32_16x16x32_bf16(aptr[kt * 4], bptr[kt * 4], acc1, 0, 0, 0);
        f32x4 acc = acc0 + acc1;
        int o = w * 16 + row16;
        float bias = sNet[176 + o];
        float4 res;
        res.x = leaky(acc[0] + bias);
        res.y = leaky(acc[1] + bias);
        res.z = leaky(acc[2] + bias);
        res.w = leaky(acc[3] + bias);
        *(float4*)(out + (long)(b * COUT + o) * HWv + n0 + kgrp * 4) = res;
    }
}

extern "C" void kernel_launch(void* const* d_in, const int* in_sizes, int n_in,
                              void* d_out, int out_size, void* d_ws, size_t ws_size,
                              hipStream_t stream) {
    const float* xyz      = (const float*)d_in[0];
    const float* features = (const float*)d_in[1];
    const float* sampled  = (const float*)d_in[2];
    const int*   knn_idx  = (const int*)  d_in[3];
    const int*   mask     = (const int*)  d_in[4];
    const float* w1       = (const float*)d_in[5];
    const float* b1       = (const float*)d_in[6];
    const float* w2       = (const float*)d_in[7];
    const float* b2       = (const float*)d_in[8];
    const float* w_lin    = (const float*)d_in[9];
    const float* b_lin    = (const float*)d_in[10];
    float* out = (float*)d_out;

    unsigned short* feats_bf = (unsigned short*)d_ws;
    float* xyz_cl = (float*)((char*)d_ws + (size_t)Bv * HWv * 64 * 2);
    unsigned short* wl_bf = (unsigned short*)((char*)xyz_cl + (size_t)Bv * HWv * 4 * 4);

    transpose_kernel<<<Bv * 560, 256, 0, stream>>>(xyz, features, feats_bf, xyz_cl);
    wl_bf16_kernel<<<(COUT * KDIM + 255) / 256, 256, 0, stream>>>(w_lin, wl_bf);
    pointconv_main<<<Bv * NBLK_PER_B, 256, 0, stream>>>(feats_bf, xyz_cl, wl_bf, knn_idx, mask,
                                                        sampled, w1, b1, w2, b2, b_lin, out);
}

// Round 11
// 136.750 us; speedup vs baseline: 5.7803x; 1.0658x over previous
//
#include <hip/hip_runtime.h>
#include <hip/hip_bf16.h>

#define HWv   35840   // H*W = 160*224
#define NPTS  35840
#define Bv    2
#define Kv    16
#define CP3   67
#define COUT  64
#define PPB   16
#define NBLK_PER_B (NPTS / PPB)   // 2240
#define KDIM  1088    // 16 f * 68 c   (c: 0-63 features, 64-66 xyz, 67 pad)
#define ASTR  1096    // sAgg row stride (bf16 elems); 2192 B, 16B-aligned
#define WTSTR 264     // sWt p-stride in f32
#define LDSPAD 3712   // pushes block LDS past 40960 B -> allocator targets
                      // 3 blocks/CU -> VGPR budget ~170 (R10 evidence), so the
                      // 16-deep register prefetch doesn't spill (R4-R9 lesson)

typedef __attribute__((ext_vector_type(4))) float  f32x4;
typedef __attribute__((ext_vector_type(8))) short  bf16x8;

static __device__ __forceinline__ unsigned short f2bf(float f) {
    unsigned int u = __float_as_uint(f);
    unsigned int r = (u + 0x7FFFu + ((u >> 16) & 1u)) >> 16;   // RNE
    return (unsigned short)r;
}
static __device__ __forceinline__ float leaky(float v) { return v >= 0.f ? v : 0.1f * v; }

// ---- kernel 1: channel-last bf16 features [B][HW][64] + f32 xyz [B][HW][4] ----
__global__ __launch_bounds__(256) void transpose_kernel(const float* __restrict__ xyz,
                                                        const float* __restrict__ feat,
                                                        unsigned short* __restrict__ feats_bf,
                                                        float* __restrict__ xyz_cl) {
    __shared__ float tile[68][65];
    int t = threadIdx.x;
    int blk = blockIdx.x;                 // Bv * 560
    int b = blk / 560;
    int hw0 = (blk % 560) * 64;
    int j = t & 63, cq = t >> 6;
    for (int cc = 0; cc < 17; ++cc) {
        int c = cc * 4 + cq;              // 0..67
        float v = 0.f;
        if (c < 64)      v = feat[((long)b * 64 + c) * HWv + hw0 + j];
        else if (c < 67) v = xyz[((long)b * 3 + (c - 64)) * HWv + hw0 + j];
        tile[c][j] = v;
    }
    __syncthreads();
    int r = t >> 2, q = t & 3;
    unsigned short* dst = feats_bf + ((long)b * HWv + hw0 + r) * 64;
    #pragma unroll
    for (int i = q; i < 16; i += 4) {
        ushort4 v;
        v.x = f2bf(tile[i * 4 + 0][r]); v.y = f2bf(tile[i * 4 + 1][r]);
        v.z = f2bf(tile[i * 4 + 2][r]); v.w = f2bf(tile[i * 4 + 3][r]);
        *(ushort4*)(dst + i * 4) = v;
    }
    if (q == 0) {
        float4 x4 = make_float4(tile[64][r], tile[65][r], tile[66][r], 0.f);
        *(float4*)(xyz_cl + ((long)b * HWv + hw0 + r) * 4) = x4;
    }
}

// ---- kernel 1b: w_lin -> bf16 [64][1088], channel-remapped to match sAgg ----
__global__ __launch_bounds__(256) void wl_bf16_kernel(const float* __restrict__ w_lin,
                                                      unsigned short* __restrict__ wl_bf) {
    int e = blockIdx.x * 256 + threadIdx.x;   // 64*1088 = 69632
    if (e >= COUT * KDIM) return;
    int o  = e / KDIM;
    int fc = e - o * KDIM;
    int f  = fc / 68;
    int c  = fc - f * 68;
    float v = 0.f;
    if (c < 64)      v = w_lin[o * (16 * CP3) + f * CP3 + 3 + c];    // feature channels
    else if (c < 67) v = w_lin[o * (16 * CP3) + f * CP3 + (c - 64)]; // xyz channels
    wl_bf[e] = f2bf(v);
}

// ---- kernel 2: fused gather + weightnet + agg + MFMA linear ----
__global__ __launch_bounds__(256) void pointconv_main(
        const unsigned short* __restrict__ feats_bf,
        const float*  __restrict__ xyz_cl,
        const unsigned short* __restrict__ wl_bf,
        const int*    __restrict__ knn_idx,
        const int*    __restrict__ mask,
        const float*  __restrict__ sampled,
        const float*  __restrict__ w1,
        const float*  __restrict__ b1,
        const float*  __restrict__ w2,
        const float*  __restrict__ b2,
        const float*  __restrict__ b_lin,
        float*        __restrict__ out) {
    // lifetime-union region: [sXyz 3072 | sWt 16896] overlaid later by sAgg 35072
    // + LDSPAD dead bytes to cross the 40 KB allocator threshold (see #define)
    __shared__ __align__(16) char sBuf[PPB * ASTR * 2 + LDSPAD];
    __shared__ int   sRow[PPB][Kv];
    __shared__ float sNx[PPB][4];
    __shared__ float sNet[240];        // w1(24) b1(8) w2(128) b2(16) b_lin(64)

    float* sXyz = (float*)sBuf;                      // [p][k][3]
    float* sWt  = (float*)(sBuf + 3072);             // [p][k*16+f], p-stride 264
    unsigned short* sAgg = (unsigned short*)sBuf;    // [p][1096]

    int t = threadIdx.x;
    int blk = blockIdx.x;
    int b = blk / NBLK_PER_B;
    int n0 = (blk % NBLK_PER_B) * PPB;
    int p = t >> 4, u = t & 15;
    int w = t >> 6, l = t & 63;

    // ---- P0: metadata + params ----
    int base = (b * NPTS + n0 + p) * Kv + u;
    int g = knn_idx[base];
    float mf = mask[base] ? 1.f : 0.f;
    int row = b * HWv + g;
    sRow[p][u] = row * 128;                          // byte offset into feats_bf
    float4 x4 = *(const float4*)(xyz_cl + (long)row * 4);
    float xd0 = x4.x * mf, xd1 = x4.y * mf, xd2 = x4.z * mf;
    {
        float* xs = sXyz + (p * Kv + u) * 3;
        xs[0] = xd0; xs[1] = xd1; xs[2] = xd2;
    }
    if (t < 240) {
        float v;
        if (t < 24)       v = w1[t];
        else if (t < 32)  v = b1[t - 24];
        else if (t < 160) v = w2[t - 32];
        else if (t < 176) v = b2[t - 160];
        else              v = b_lin[t - 176];
        sNet[t] = v;
    }
    if (t < PPB * 3) { int pp = t / 3, c = t - pp * 3; sNx[pp][c] = sampled[(b * 3 + c) * HWv + n0 + pp]; }
    __syncthreads();

    // ---- issue ALL 16 gather loads now (named regs, statically indexed); ----
    // ---- P1's ~400 VALU cycles hide the L2/L3 latency                    ----
    const char* fb = (const char*)feats_bf;
    #define LOADK(K) uint2 v##K = *(const uint2*)(fb + sRow[p][K] + (u << 3))
    LOADK(0);  LOADK(1);  LOADK(2);  LOADK(3);
    LOADK(4);  LOADK(5);  LOADK(6);  LOADK(7);
    LOADK(8);  LOADK(9);  LOADK(10); LOADK(11);
    LOADK(12); LOADK(13); LOADK(14); LOADK(15);
    #undef LOADK

    // ---- P1: weight net, thread = (p,k=u); coords from own registers ----
    {
        const float* W1 = sNet;
        const float* B1 = sNet + 24;
        const float* W2 = sNet + 32;
        const float* B2 = sNet + 160;
        float r0 = xd0 - sNx[p][0];
        float r1 = xd1 - sNx[p][1];
        float r2 = xd2 - sNx[p][2];
        float h[8];
        #pragma unroll
        for (int i = 0; i < 8; ++i)
            h[i] = leaky(W1[i * 3] * r0 + W1[i * 3 + 1] * r1 + W1[i * 3 + 2] * r2 + B1[i]);
        float wk[16];
        #pragma unroll
        for (int f = 0; f < 16; ++f) {
            float v = B2[f];
            #pragma unroll
            for (int i = 0; i < 8; ++i) v += W2[f * 8 + i] * h[i];
            wk[f] = leaky(v) * mf;                   // mask folded into weight
        }
        f32x4* wdst = (f32x4*)(sWt + p * WTSTR + u * 16);
        wdst[0] = (f32x4){wk[0], wk[1], wk[2], wk[3]};
        wdst[1] = (f32x4){wk[4], wk[5], wk[6], wk[7]};
        wdst[2] = (f32x4){wk[8], wk[9], wk[10], wk[11]};
        wdst[3] = (f32x4){wk[12], wk[13], wk[14], wk[15]};
    }
    __syncthreads();

    // ---- P2: aggregation. thread = (p,u); u owns feature channels 4u..4u+3 ----
    float agg[16][4];
    #pragma unroll
    for (int f = 0; f < 16; ++f)
        #pragma unroll
        for (int c = 0; c < 4; ++c) agg[f][c] = 0.f;
    float ax = 0.f, ay = 0.f, az = 0.f;              // xyz-channel agg (f = u role)

    #define AGGSTEP(K, V) do {                                                      \
        float fv0 = __uint_as_float((V).x << 16);                                   \
        float fv1 = __uint_as_float((V).x & 0xffff0000u);                           \
        float fv2 = __uint_as_float((V).y << 16);                                   \
        float fv3 = __uint_as_float((V).y & 0xffff0000u);                           \
        const f32x4* wt4 = (const f32x4*)(sWt + p * WTSTR + (K) * 16);              \
        f32x4 w0 = wt4[0], w1v = wt4[1], w2v = wt4[2], w3v = wt4[3];                \
        _Pragma("unroll")                                                           \
        for (int c = 0; c < 4; ++c) {                                               \
            float fv = c == 0 ? fv0 : c == 1 ? fv1 : c == 2 ? fv2 : fv3;            \
            agg[0][c]  += w0[0] * fv;  agg[1][c]  += w0[1] * fv;                    \
            agg[2][c]  += w0[2] * fv;  agg[3][c]  += w0[3] * fv;                    \
            agg[4][c]  += w1v[0] * fv; agg[5][c]  += w1v[1] * fv;                   \
            agg[6][c]  += w1v[2] * fv; agg[7][c]  += w1v[3] * fv;                   \
            agg[8][c]  += w2v[0] * fv; agg[9][c]  += w2v[1] * fv;                   \
            agg[10][c] += w2v[2] * fv; agg[11][c] += w2v[3] * fv;                   \
            agg[12][c] += w3v[0] * fv; agg[13][c] += w3v[1] * fv;                   \
            agg[14][c] += w3v[2] * fv; agg[15][c] += w3v[3] * fv;                   \
        }                                                                           \
        float wtv = sWt[p * WTSTR + (K) * 16 + u];                                  \
        const float* xs = sXyz + (p * Kv + (K)) * 3;                                \
        ax += wtv * xs[0]; ay += wtv * xs[1]; az += wtv * xs[2];                    \
    } while (0)

    AGGSTEP(0, v0);   AGGSTEP(1, v1);   AGGSTEP(2, v2);   AGGSTEP(3, v3);
    AGGSTEP(4, v4);   AGGSTEP(5, v5);   AGGSTEP(6, v6);   AGGSTEP(7, v7);
    AGGSTEP(8, v8);   AGGSTEP(9, v9);   AGGSTEP(10, v10); AGGSTEP(11, v11);
    AGGSTEP(12, v12); AGGSTEP(13, v13); AGGSTEP(14, v14); AGGSTEP(15, v15);
    #undef AGGSTEP
    __syncthreads();      // all waves done reading sWt/sXyz; sAgg may overlay

    // ---- write agg -> bf16 LDS ----
    {
        #pragma unroll
        for (int f = 0; f < 16; ++f) {
            ushort4 hv;
            hv.x = f2bf(agg[f][0]); hv.y = f2bf(agg[f][1]);
            hv.z = f2bf(agg[f][2]); hv.w = f2bf(agg[f][3]);
            *(ushort4*)&sAgg[p * ASTR + f * 68 + u * 4] = hv;
        }
        ushort4 hx;
        hx.x = f2bf(ax); hx.y = f2bf(ay); hx.z = f2bf(az); hx.w = 0;
        *(ushort4*)&sAgg[p * ASTR + u * 68 + 64] = hx;   // thread acts as f=u here
    }
    __syncthreads();

    // ---- P3: MFMA  out[16 pts][64 outs] = sAgg[16][1088] x wl_bf[64][1088]^T ----
    {
        int row16 = l & 15;
        int kgrp  = l >> 4;
        const bf16x8* aptr = (const bf16x8*)&sAgg[row16 * ASTR + kgrp * 8];
        const bf16x8* bptr = (const bf16x8*)(wl_bf + (w * 16 + row16) * KDIM + kgrp * 8);
        f32x4 acc0 = {0.f, 0.f, 0.f, 0.f}, acc1 = {0.f, 0.f, 0.f, 0.f};
        #pragma unroll
        for (int kt = 0; kt < 17; ++kt)
            acc0 = __builtin_amdgcn_mfma_f32_16x16x32_bf16(aptr[kt * 4], bptr[kt * 4], acc0, 0, 0, 0);
        #pragma unroll
        for (int kt = 17; kt < 34; ++kt)
            acc1 = __builtin_amdgcn_mfma_f32_16x16x32_bf16(aptr[kt * 4], bptr[kt * 4], acc1, 0, 0, 0);
        f32x4 acc = acc0 + acc1;
        int o = w * 16 + row16;
        float bias = sNet[176 + o];
        float4 res;
        res.x = leaky(acc[0] + bias);
        res.y = leaky(acc[1] + bias);
        res.z = leaky(acc[2] + bias);
        res.w = leaky(acc[3] + bias);
        *(float4*)(out + (long)(b * COUT + o) * HWv + n0 + kgrp * 4) = res;
    }
}

extern "C" void kernel_launch(void* const* d_in, const int* in_sizes, int n_in,
                              void* d_out, int out_size, void* d_ws, size_t ws_size,
                              hipStream_t stream) {
    const float* xyz      = (const float*)d_in[0];
    const float* features = (const float*)d_in[1];
    const float* sampled  = (const float*)d_in[2];
    const int*   knn_idx  = (const int*)  d_in[3];
    const int*   mask     = (const int*)  d_in[4];
    const float* w1       = (const float*)d_in[5];
    const float* b1       = (const float*)d_in[6];
    const float* w2       = (const float*)d_in[7];
    const float* b2       = (const float*)d_in[8];
    const float* w_lin    = (const float*)d_in[9];
    const float* b_lin    = (const float*)d_in[10];
    float* out = (float*)d_out;

    unsigned short* feats_bf = (unsigned short*)d_ws;
    float* xyz_cl = (float*)((char*)d_ws + (size_t)Bv * HWv * 64 * 2);
    unsigned short* wl_bf = (unsigned short*)((char*)xyz_cl + (size_t)Bv * HWv * 4 * 4);

    transpose_kernel<<<Bv * 560, 256, 0, stream>>>(xyz, features, feats_bf, xyz_cl);
    wl_bf16_kernel<<<(COUT * KDIM + 255) / 256, 256, 0, stream>>>(w_lin, wl_bf);
    pointconv_main<<<Bv * NBLK_PER_B, 256, 0, stream>>>(feats_bf, xyz_cl, wl_bf, knn_idx, mask,
                                                        sampled, w1, b1, w2, b2, b_lin, out);
}